// Round 11
// baseline (264.723 us; speedup 1.0000x reference)
//
#include <hip/hip_runtime.h>

#define N_NODES 50000
#define N_EDGES 800000
#define D 128
#define CAP 48                        // max in-degree slots (verified sufficient R2-R8)
#define NPADN 50176                   // padded node count (196*256)

#define PACKB 24                      // W-pack blocks (96 wids)

// ---- deterministic sort-repaired build (R10 mechanism, R4 speed) ----
#define ABLK 400                      // edge blocks
#define AEDGES (N_EDGES / ABLK)       // 2000 edges per block (exact)
#define DBW 256                       // dst-bucket width; bucket = d>>8
#define DNB 196                       // 50176/256 dst buckets
#define DCAP 6144                     // per-dst-bucket capacity (mean 4082, +32 sigma)
// ---- src-side binning for odeg (order-independent histogram, proven R7) ----
#define SBW 512                       // src bin width; bin = s>>9
#define SNB 98                        // ceil(50176/512)
#define BCAP 10240                    // per-src-bin capacity (mean 8163, +23 sigma)

typedef __attribute__((ext_vector_type(4))) float f32x4;
typedef __attribute__((ext_vector_type(8))) short s16x8;

__device__ inline unsigned short f32_to_bf16_rtne(float f) {
    union { float f; unsigned u; } c; c.f = f;
    unsigned u = c.u;
    u += 0x7FFF + ((u >> 16) & 1);
    return (unsigned short)(u >> 16);
}
__device__ inline float bf16_to_f32(unsigned short h) {
    union { unsigned u; float f; } c; c.u = ((unsigned)h) << 16;
    return c.f;
}
__device__ inline unsigned pack_bf2(float a, float b) {
    return (unsigned)f32_to_bf16_rtne(a) | ((unsigned)f32_to_bf16_rtne(b) << 16);
}
__device__ inline void unpack_bf2(unsigned u, float& a, float& b) {
    union { unsigned u; float f; } c0, c1;
    c0.u = u << 16; c1.u = u & 0xFFFF0000u;
    a = c0.f; b = c1.f;
}
__device__ inline void acc_uint4(uint4 v, float* a) {
    float f0, f1;
    unpack_bf2(v.x, f0, f1); a[0] += f0; a[1] += f1;
    unpack_bf2(v.y, f0, f1); a[2] += f0; a[3] += f1;
    unpack_bf2(v.z, f0, f1); a[4] += f0; a[5] += f1;
    unpack_bf2(v.w, f0, f1); a[6] += f0; a[7] += f1;
}

// ---------------- K1: single-pass bin by dst (u64 payload) | src binning | W-pack ----------------
// R10 proved: determinism needs ONLY fill_sort's per-node sort on unique edge-id keys --
// the intermediate dbin order is irrelevant. So the R10 scan (serial, ~25us on one CU) is
// deleted and runs are reserved with a single inter-block atomicAdd (R4's fast path).
// Payload = (edge_id<<32)|(d&255)<<16|src; per-bucket overflow margin 32 sigma.

__global__ __launch_bounds__(256) void build_bin(const int* __restrict__ src,
                                                 const int* __restrict__ dst,
                                                 int* __restrict__ gcurD,
                                                 int* __restrict__ gcurS,
                                                 unsigned long long* __restrict__ dbin,
                                                 unsigned short* __restrict__ sbin,
                                                 const float* __restrict__ W0,
                                                 const float* __restrict__ W1,
                                                 const float* __restrict__ W2,
                                                 s16x8* __restrict__ wpk) {
    int b = blockIdx.x;
    if (b < ABLK) {
        __shared__ int cntD[DNB], baseD[DNB], c2D[DNB];
        __shared__ int cntS[SNB], baseS[SNB], c2S[SNB];
        for (int i = threadIdx.x; i < DNB; i += 256) { cntD[i] = 0; c2D[i] = 0; }
        for (int i = threadIdx.x; i < SNB; i += 256) { cntS[i] = 0; c2S[i] = 0; }
        __syncthreads();
        int e0 = b * AEDGES;
        for (int i = threadIdx.x; i < AEDGES; i += 256) {
            int s = src[e0 + i], d = dst[e0 + i];
            atomicAdd(&cntD[d >> 8], 1);
            atomicAdd(&cntS[s >> 9], 1);
        }
        __syncthreads();
        for (int i = threadIdx.x; i < DNB; i += 256) baseD[i] = atomicAdd(&gcurD[i], cntD[i]);
        for (int i = threadIdx.x; i < SNB; i += 256) baseS[i] = atomicAdd(&gcurS[i], cntS[i]);
        __syncthreads();
        for (int i = threadIdx.x; i < AEDGES; i += 256) {
            int e = e0 + i;
            int s = src[e], d = dst[e];
            int bd = d >> 8;
            int rd = atomicAdd(&c2D[bd], 1);
            int od = baseD[bd] + rd;
            if (od < DCAP)
                dbin[(size_t)bd * DCAP + od] =
                    ((unsigned long long)(unsigned)e << 32) | ((unsigned)(d & 255) << 16) | (unsigned)s;
            int bs = s >> 9;
            int rs = atomicAdd(&c2S[bs], 1);
            int os = baseS[bs] + rs;
            if (os < BCAP) sbin[bs * BCAP + os] = (unsigned short)s;
        }
    } else {
        // ---- W-pack role ----
        int wid = (b - ABLK) * 4 + (threadIdx.x >> 6);   // 0..95 = layer(3) x ct(8) x ks(4)
        if (wid >= 96) return;
        int lane = threadIdx.x & 63;
        int layer = wid / 32, rem = wid % 32;
        int ct = rem >> 2, ks = rem & 3;
        const float* W = (layer == 0) ? W0 : (layer == 1) ? W1 : W2;
        int col = ct * 16 + (lane & 15);
        int k0  = ks * 32 + (lane >> 4) * 8;
        s16x8 hi, lo;
#pragma unroll
        for (int j = 0; j < 8; j++) {
            float w = W[(k0 + j) * D + col];
            unsigned short h = f32_to_bf16_rtne(w);
            hi[j] = (short)h;
            lo[j] = (short)f32_to_bf16_rtne(w - bf16_to_f32(h));
        }
        int idx = layer * 4096 + (ct * 4 + ks) * 64 + lane;
        wpk[idx]        = hi;
        wpk[idx + 2048] = lo;
    }
}

// ---------------- K2: per-bucket slot fill + per-node edge-id sort (b<DNB) | odeg hist ----------------
// Determinism anchor (proven R10, ~70 replays): per-node insertion sort on UNIQUE edge-id
// keys -> slots bit-identical every replay regardless of intra-bucket placement races.

__global__ __launch_bounds__(256) void fill_sort(const unsigned long long* __restrict__ dbin,
                                                 const int* __restrict__ gcurD,
                                                 unsigned short* __restrict__ slots,  // padded NPADN rows
                                                 int* __restrict__ cursor,            // padded NPADN
                                                 const unsigned short* __restrict__ sbin,
                                                 const int* __restrict__ gcurS,
                                                 int* __restrict__ odeg) {
    __shared__ unsigned key[256 * 49];        // stride 49 (pad) to soften sort bank aliasing
    __shared__ unsigned short sv[256 * CAP];
    __shared__ int cur[256];
    __shared__ int scnt[SBW];
    int b = blockIdx.x;
    if (b < DNB) {
        int t = threadIdx.x;
        cur[t] = 0;
        __syncthreads();
        int n = min(gcurD[b], DCAP);
        const unsigned long long* eb = dbin + (size_t)b * DCAP;
        for (int i = t; i < n; i += 256) {
            unsigned long long w = eb[i];
            int dl = (int)((w >> 16) & 255);
            int p = atomicAdd(&cur[dl], 1);
            if (p < CAP) {
                key[dl * 49 + p] = (unsigned)(w >> 32);
                sv[dl * CAP + p] = (unsigned short)(w & 0xFFFFu);
            }
        }
        __syncthreads();
        // per-node insertion sort by edge id (unique keys -> deterministic final order)
        {
            int m = min(cur[t], CAP);
            int bk = t * 49, bs = t * CAP;
            for (int i = 1; i < m; i++) {
                unsigned ki = key[bk + i];
                unsigned short si = sv[bs + i];
                int j = i - 1;
                while (j >= 0 && key[bk + j] > ki) {
                    key[bk + j + 1] = key[bk + j];
                    sv[bs + j + 1] = sv[bs + j];
                    j--;
                }
                key[bk + j + 1] = ki;
                sv[bs + j + 1] = si;
            }
        }
        __syncthreads();
        int n0 = b * DBW;
        unsigned* dw = (unsigned*)(slots + (size_t)n0 * CAP);
        const unsigned* sw = (const unsigned*)sv;
        for (int i = t; i < DBW * CAP / 2; i += 256) dw[i] = sw[i];
        cursor[n0 + t] = cur[t];
    } else {
        // ---- odeg histogram role (order-independent, proven R7) ----
        int bb = b - DNB;                     // 0..97
        for (int i = threadIdx.x; i < SBW; i += 256) scnt[i] = 0;
        __syncthreads();
        int nE = min(gcurS[bb], BCAP);
        const unsigned short* es = sbin + (size_t)bb * BCAP;
        for (int i = threadIdx.x; i < nE; i += 256)
            atomicAdd(&scnt[es[i] & (SBW - 1)], 1);
        __syncthreads();
        int n0 = bb * SBW;
        for (int i = threadIdx.x; i < SBW; i += 256)
            if (n0 + i < N_NODES) odeg[n0 + i] = scnt[i];
    }
}

// ---------------- h -> bf16 rows pre-scaled by s_out (computed in-kernel from odeg) ----------------

__global__ __launch_bounds__(256) void hconv(const float4* __restrict__ h,
                                             const int* __restrict__ odeg,
                                             float* __restrict__ s_out,
                                             uint2* __restrict__ hbA,
                                             uint2* __restrict__ hbB) {
    int gid = blockIdx.x * 256 + threadIdx.x;   // one float4 (4 channels) per thread
    const int total = N_NODES * 32;
    if (gid < total) {
        int node = gid >> 5;
        float so = rsqrtf(fmaxf((float)odeg[node], 1.0f));
        if ((gid & 31) == 0) s_out[node] = so;   // persist for fused_layer epilogue
        float4 v = h[gid];
        hbA[gid] = make_uint2(pack_bf2(so * v.x, so * v.y), pack_bf2(so * v.z, so * v.w));
    } else if (gid < total + 32) {
        hbA[total + (gid - total)] = make_uint2(0u, 0u);        // zero row of actA
    } else if (gid < total + 64) {
        hbB[total + (gid - total - 32)] = make_uint2(0u, 0u);   // zero row of actB
    }
}

// ---------------- fused layer: gather-aggregate -> LDS(split-bf16) -> MFMA GEMM (R7 form) ----------------

__global__ __launch_bounds__(256) void fused_layer(const uint4* __restrict__ x,
                                                   const unsigned short* __restrict__ slots,
                                                   const int* __restrict__ deg,
                                                   const s16x8* __restrict__ wpk,
                                                   const float* __restrict__ bias,
                                                   const float* __restrict__ s_out,
                                                   float* __restrict__ outf,
                                                   unsigned short* __restrict__ outb) {
    __shared__ s16x8 mHI[16 * 17];
    __shared__ s16x8 mLO[16 * 17];
    int tid = threadIdx.x;
    int row0 = blockIdx.x * 16;

    // ---- phase 1: aggregate ----
    {
        int nloc = tid >> 4;          // local node 0..15
        int l    = tid & 15;          // chunk: channels l*8 .. l*8+7
        int node = row0 + nloc;
        int dgraw = deg[node];
        int dg = min(dgraw, CAP);
        int base = node * CAP;
        // prefetch all slot indices; OOB -> zero row
        int idx0 = (l      < dg) ? (int)slots[base + l]      : N_NODES;
        int idx1 = (16 + l < dg) ? (int)slots[base + 16 + l] : N_NODES;
        int idx2 = (32 + l < dg) ? (int)slots[base + 32 + l] : N_NODES;

        float a[8];
#pragma unroll
        for (int j = 0; j < 8; j++) a[j] = 0.f;

        int nr = (dg + 7) >> 3;       // rounds of 8 (0..6), no tails
        for (int r = 0; r < nr; r++) {
            int c = r >> 1;
            int v = (c == 0) ? idx0 : ((c == 1) ? idx1 : idx2);
            int k = (r & 1) * 8;
            int s0 = __shfl(v, k + 0, 16), s1 = __shfl(v, k + 1, 16);
            int s2 = __shfl(v, k + 2, 16), s3 = __shfl(v, k + 3, 16);
            int s4 = __shfl(v, k + 4, 16), s5 = __shfl(v, k + 5, 16);
            int s6 = __shfl(v, k + 6, 16), s7 = __shfl(v, k + 7, 16);
            uint4 g0 = x[s0 * 16 + l];
            uint4 g1 = x[s1 * 16 + l];
            uint4 g2 = x[s2 * 16 + l];
            uint4 g3 = x[s3 * 16 + l];
            uint4 g4 = x[s4 * 16 + l];
            uint4 g5 = x[s5 * 16 + l];
            uint4 g6 = x[s6 * 16 + l];
            uint4 g7 = x[s7 * 16 + l];
            acc_uint4(g0, a); acc_uint4(g1, a); acc_uint4(g2, a); acc_uint4(g3, a);
            acc_uint4(g4, a); acc_uint4(g5, a); acc_uint4(g6, a); acc_uint4(g7, a);
        }
        float si = rsqrtf(fmaxf((float)dgraw, 1.0f));
        s16x8 ahi, alo;
#pragma unroll
        for (int j = 0; j < 8; j++) {
            float av = a[j] * si;
            unsigned short hh = f32_to_bf16_rtne(av);
            ahi[j] = (short)hh;
            alo[j] = (short)f32_to_bf16_rtne(av - bf16_to_f32(hh));
        }
        mHI[nloc * 17 + l] = ahi;
        mLO[nloc * 17 + l] = alo;
    }
    __syncthreads();

    // ---- phase 2: GEMM ----
    int wv = tid >> 6;                 // wave 0..3 -> col-tiles {2wv, 2wv+1}
    int lane = tid & 63;
    int arow = lane & 15, aq = lane >> 4;
    int ct0 = wv * 2, ct1 = ct0 + 1;
    f32x4 acc0 = (f32x4)0.f, acc1 = (f32x4)0.f;

#pragma unroll
    for (int ks = 0; ks < 4; ks++) {
        s16x8 ahi = mHI[arow * 17 + ks * 4 + aq];
        s16x8 alo = mLO[arow * 17 + ks * 4 + aq];
        int idx0 = (ct0 * 4 + ks) * 64 + lane;
        int idx1 = (ct1 * 4 + ks) * 64 + lane;
        s16x8 b0h = wpk[idx0], b0l = wpk[idx0 + 2048];
        s16x8 b1h = wpk[idx1], b1l = wpk[idx1 + 2048];
        acc0 = __builtin_amdgcn_mfma_f32_16x16x32_bf16(ahi, b0h, acc0, 0, 0, 0);
        acc0 = __builtin_amdgcn_mfma_f32_16x16x32_bf16(alo, b0h, acc0, 0, 0, 0);
        acc0 = __builtin_amdgcn_mfma_f32_16x16x32_bf16(ahi, b0l, acc0, 0, 0, 0);
        acc1 = __builtin_amdgcn_mfma_f32_16x16x32_bf16(ahi, b1h, acc1, 0, 0, 0);
        acc1 = __builtin_amdgcn_mfma_f32_16x16x32_bf16(alo, b1h, acc1, 0, 0, 0);
        acc1 = __builtin_amdgcn_mfma_f32_16x16x32_bf16(ahi, b1l, acc1, 0, 0, 0);
    }

    // C/D: col = lane&15, row = (lane>>4)*4 + reg
    int crow0 = aq * 4;
    float so4[4];
    if (outb) {
#pragma unroll
        for (int r = 0; r < 4; r++) so4[r] = s_out[row0 + crow0 + r];
    }
    int colA = ct0 * 16 + arow, colB = ct1 * 16 + arow;
    float bA = bias[colA], bB = bias[colB];
#pragma unroll
    for (int r = 0; r < 4; r++) {
        size_t rowoff = (size_t)(row0 + crow0 + r) * D;
        float vA = fmaxf(acc0[r] + bA, 0.f);
        float vB = fmaxf(acc1[r] + bB, 0.f);
        if (outf) { outf[rowoff + colA] = vA; outf[rowoff + colB] = vB; }
        if (outb) {
            outb[rowoff + colA] = f32_to_bf16_rtne(so4[r] * vA);
            outb[rowoff + colB] = f32_to_bf16_rtne(so4[r] * vB);
        }
    }
}

// ---------------- launch ----------------

extern "C" void kernel_launch(void* const* d_in, const int* in_sizes, int n_in,
                              void* d_out, int out_size, void* d_ws, size_t ws_size,
                              hipStream_t stream) {
    const float* h  = (const float*)d_in[0];
    const int*  src = (const int*)d_in[1];
    const int*  dst = (const int*)d_in[2];
    const float* W0 = (const float*)d_in[3];
    const float* b0 = (const float*)d_in[4];
    const float* W1 = (const float*)d_in[5];
    const float* b1 = (const float*)d_in[6];
    const float* W2 = (const float*)d_in[7];
    const float* b2 = (const float*)d_in[8];
    float* out = (float*)d_out;

    char* w = (char*)d_ws;
    auto carve = [&](size_t bytes) -> void* {
        void* p = (void*)w;
        w += (bytes + 255) & ~(size_t)255;
        return p;
    };
    int*      gcurD   = (int*)carve((DNB + 128) * sizeof(int));    // gcurD + gcurS (one memset)
    int*      gcurS   = gcurD + DNB;
    int*      cursor  = (int*)carve(NPADN * sizeof(int));          // in-degree (padded)
    int*      odeg    = (int*)carve(N_NODES * sizeof(int));
    float*    s_out   = (float*)carve(N_NODES * sizeof(float));
    unsigned long long* dbin = (unsigned long long*)carve((size_t)DNB * DCAP * 8);   // 9.6 MB
    unsigned short* slots = (unsigned short*)carve((size_t)NPADN * CAP * sizeof(unsigned short)); // 4.8 MB
    unsigned short* sbin  = (unsigned short*)carve((size_t)SNB * BCAP * sizeof(unsigned short));  // 2.0 MB
    unsigned short* actA  = (unsigned short*)carve((size_t)(N_NODES + 1) * D * 2);  // 12.8 MB (+zero row)
    unsigned short* actB  = (unsigned short*)carve((size_t)(N_NODES + 1) * D * 2);  // 12.8 MB
    s16x8*    wpk     = (s16x8*)carve(3 * 4096 * sizeof(s16x8));                    // 192 KB

    hipMemsetAsync(gcurD, 0, (DNB + 128) * sizeof(int), stream);
    build_bin<<<ABLK + PACKB, 256, 0, stream>>>(src, dst, gcurD, gcurS, dbin, sbin,
                                                W0, W1, W2, wpk);
    fill_sort<<<DNB + SNB, 256, 0, stream>>>(dbin, gcurD, slots, cursor,
                                             sbin, gcurS, odeg);
    hconv<<<(N_NODES * 32 + 64 + 255) / 256, 256, 0, stream>>>((const float4*)h, odeg, s_out,
                                                               (uint2*)actA, (uint2*)actB);

    const int GRID = N_NODES / 16;   // 3125 exact

    // layer 1: actA(bf16, s_out-scaled h) -> actB
    fused_layer<<<GRID, 256, 0, stream>>>((const uint4*)actA, slots, cursor,
                                          wpk, b0, s_out, nullptr, actB);
    // layer 2: actB -> actA
    fused_layer<<<GRID, 256, 0, stream>>>((const uint4*)actB, slots, cursor,
                                          wpk + 4096, b1, s_out, nullptr, actA);
    // layer 3: actA -> d_out (fp32)
    fused_layer<<<GRID, 256, 0, stream>>>((const uint4*)actA, slots, cursor,
                                          wpk + 8192, b2, s_out, out, nullptr);
}

// Round 12
// 234.040 us; speedup vs baseline: 1.1311x; 1.1311x over previous
//
#include <hip/hip_runtime.h>

#define N_NODES 50000
#define N_EDGES 800000
#define D 128
#define CAP 48                        // max in-degree slots (verified sufficient R2-R8)
#define NPADN 50176                   // padded node count (196*256)

#define PACKB 24                      // W-pack blocks (96 wids)

// ---- deterministic sort-repaired build ----
#define ABLK 400                      // edge blocks
#define AEDGES (N_EDGES / ABLK)       // 2000 edges per block (exact)
#define DBW 256                       // dst-bucket width; bucket = d>>8
#define DNB 196                       // 50176/256 dst buckets
#define DCAP 6144                     // per-dst-bucket capacity (mean 4082, +32 sigma)
#define FNB (2 * DNB)                 // 392 fill blocks (half-bucket each)
#define HN 128                        // nodes per fill block
// ---- src-side binning for odeg (order-independent histogram, proven R7) ----
#define SBW 512                       // src bin width; bin = s>>9
#define SNB 98                        // ceil(50176/512)
#define BCAP 10240                    // per-src-bin capacity (mean 8163, +23 sigma)

typedef __attribute__((ext_vector_type(4))) float f32x4;
typedef __attribute__((ext_vector_type(8))) short s16x8;

__device__ inline unsigned short f32_to_bf16_rtne(float f) {
    union { float f; unsigned u; } c; c.f = f;
    unsigned u = c.u;
    u += 0x7FFF + ((u >> 16) & 1);
    return (unsigned short)(u >> 16);
}
__device__ inline float bf16_to_f32(unsigned short h) {
    union { unsigned u; float f; } c; c.u = ((unsigned)h) << 16;
    return c.f;
}
__device__ inline unsigned pack_bf2(float a, float b) {
    return (unsigned)f32_to_bf16_rtne(a) | ((unsigned)f32_to_bf16_rtne(b) << 16);
}
__device__ inline void unpack_bf2(unsigned u, float& a, float& b) {
    union { unsigned u; float f; } c0, c1;
    c0.u = u << 16; c1.u = u & 0xFFFF0000u;
    a = c0.f; b = c1.f;
}
__device__ inline void acc_uint4(uint4 v, float* a) {
    float f0, f1;
    unpack_bf2(v.x, f0, f1); a[0] += f0; a[1] += f1;
    unpack_bf2(v.y, f0, f1); a[2] += f0; a[3] += f1;
    unpack_bf2(v.z, f0, f1); a[4] += f0; a[5] += f1;
    unpack_bf2(v.w, f0, f1); a[6] += f0; a[7] += f1;
}

// ---------------- K1: single-pass bin by dst (u64 payload) | src binning | W-pack ----------------
// Determinism needs only fill_sort's per-node ranking on unique edge-id keys; dbin
// intra-bucket order is irrelevant -> single inter-block atomicAdd run reservation.

__global__ __launch_bounds__(256) void build_bin(const int* __restrict__ src,
                                                 const int* __restrict__ dst,
                                                 int* __restrict__ gcurD,
                                                 int* __restrict__ gcurS,
                                                 unsigned long long* __restrict__ dbin,
                                                 unsigned short* __restrict__ sbin,
                                                 const float* __restrict__ W0,
                                                 const float* __restrict__ W1,
                                                 const float* __restrict__ W2,
                                                 s16x8* __restrict__ wpk) {
    int b = blockIdx.x;
    if (b < ABLK) {
        __shared__ int cntD[DNB], baseD[DNB], c2D[DNB];
        __shared__ int cntS[SNB], baseS[SNB], c2S[SNB];
        for (int i = threadIdx.x; i < DNB; i += 256) { cntD[i] = 0; c2D[i] = 0; }
        for (int i = threadIdx.x; i < SNB; i += 256) { cntS[i] = 0; c2S[i] = 0; }
        __syncthreads();
        int e0 = b * AEDGES;
        for (int i = threadIdx.x; i < AEDGES; i += 256) {
            int s = src[e0 + i], d = dst[e0 + i];
            atomicAdd(&cntD[d >> 8], 1);
            atomicAdd(&cntS[s >> 9], 1);
        }
        __syncthreads();
        for (int i = threadIdx.x; i < DNB; i += 256) baseD[i] = atomicAdd(&gcurD[i], cntD[i]);
        for (int i = threadIdx.x; i < SNB; i += 256) baseS[i] = atomicAdd(&gcurS[i], cntS[i]);
        __syncthreads();
        for (int i = threadIdx.x; i < AEDGES; i += 256) {
            int e = e0 + i;
            int s = src[e], d = dst[e];
            int bd = d >> 8;
            int rd = atomicAdd(&c2D[bd], 1);
            int od = baseD[bd] + rd;
            if (od < DCAP)
                dbin[(size_t)bd * DCAP + od] =
                    ((unsigned long long)(unsigned)e << 32) | ((unsigned)(d & 255) << 16) | (unsigned)s;
            int bs = s >> 9;
            int rs = atomicAdd(&c2S[bs], 1);
            int os = baseS[bs] + rs;
            if (os < BCAP) sbin[bs * BCAP + os] = (unsigned short)s;
        }
    } else {
        // ---- W-pack role ----
        int wid = (b - ABLK) * 4 + (threadIdx.x >> 6);   // 0..95 = layer(3) x ct(8) x ks(4)
        if (wid >= 96) return;
        int lane = threadIdx.x & 63;
        int layer = wid / 32, rem = wid % 32;
        int ct = rem >> 2, ks = rem & 3;
        const float* W = (layer == 0) ? W0 : (layer == 1) ? W1 : W2;
        int col = ct * 16 + (lane & 15);
        int k0  = ks * 32 + (lane >> 4) * 8;
        s16x8 hi, lo;
#pragma unroll
        for (int j = 0; j < 8; j++) {
            float w = W[(k0 + j) * D + col];
            unsigned short h = f32_to_bf16_rtne(w);
            hi[j] = (short)h;
            lo[j] = (short)f32_to_bf16_rtne(w - bf16_to_f32(h));
        }
        int idx = layer * 4096 + (ct * 4 + ks) * 64 + lane;
        wpk[idx]        = hi;
        wpk[idx + 2048] = lo;
    }
}

// ---------------- K2: half-bucket slot fill + RANK-COUNT placement (b<FNB) | odeg hist ----------------
// R11 lesson: per-lane insertion sort = serial DEPENDENT LDS chain (worst lane ~1150
// steps x ~60cy stalls the wave -> 56us, 2M bank-conflict cycles). Rank-by-counting has
// identical deterministic result (unique edge-id keys) but all comparisons independent
// -> throughput-bound. Half-bucket blocks (128 nodes, 2 lanes/node) cut LDS 77->53KB
// (3 blocks/CU) and per-thread work 4x. key reads stride 49 words -> conflict-free.

__global__ __launch_bounds__(256) void fill_sort(const unsigned long long* __restrict__ dbin,
                                                 const int* __restrict__ gcurD,
                                                 unsigned short* __restrict__ slots,  // padded NPADN rows
                                                 int* __restrict__ cursor,            // padded NPADN
                                                 const unsigned short* __restrict__ sbin,
                                                 const int* __restrict__ gcurS,
                                                 int* __restrict__ odeg) {
    __shared__ unsigned key[HN * 49];          // 25.1 KB (pad 49: conflict-free lane access)
    __shared__ unsigned short sv[HN * 48];     // 12.3 KB (arrival-order values)
    __shared__ unsigned short sv2[HN * 50];    // 12.8 KB (ranked values, stride-50 pad)
    __shared__ int cur[HN];
    __shared__ int scnt[SBW];
    int b = blockIdx.x;
    if (b < FNB) {
        int bucket = b >> 1, half = b & 1;
        int t = threadIdx.x;
        if (t < HN) cur[t] = 0;
        __syncthreads();
        int n = min(gcurD[bucket], DCAP);
        const unsigned long long* eb = dbin + (size_t)bucket * DCAP;
        for (int i = t; i < n; i += 256) {
            unsigned long long w = eb[i];
            int dl = (int)((w >> 16) & 255);
            if ((dl >> 7) == half) {
                int d2 = dl & (HN - 1);
                int p = atomicAdd(&cur[d2], 1);
                if (p < CAP) {
                    key[d2 * 49 + p] = (unsigned)(w >> 32);
                    sv[d2 * 48 + p] = (unsigned short)(w & 0xFFFFu);
                }
            }
        }
        __syncthreads();
        // deterministic rank-count placement: pos(i) = #{j: key[j] < key[i]} (keys unique)
        {
            int node = t & (HN - 1), sub = t >> 7;
            int m = min(cur[node], CAP);
            int kb = node * 49, vb = node * 48, ob = node * 50;
            for (int i = sub; i < m; i += 2) {
                unsigned ki = key[kb + i];
                int r = 0;
#pragma unroll 4
                for (int j = 0; j < m; j++) r += (key[kb + j] < ki) ? 1 : 0;
                sv2[ob + r] = sv[vb + i];
            }
        }
        __syncthreads();
        int n0 = bucket * DBW + half * HN;
        unsigned* dw = (unsigned*)(slots + (size_t)n0 * CAP);
        for (int idx = t; idx < HN * (CAP / 2); idx += 256) {
            int node = idx / (CAP / 2);
            int w2 = idx - node * (CAP / 2);
            dw[idx] = *(const unsigned*)&sv2[node * 50 + w2 * 2];
        }
        if (t < HN) cursor[n0 + t] = cur[t];
    } else {
        // ---- odeg histogram role (order-independent, proven R7) ----
        int bb = b - FNB;                     // 0..97
        for (int i = threadIdx.x; i < SBW; i += 256) scnt[i] = 0;
        __syncthreads();
        int nE = min(gcurS[bb], BCAP);
        const unsigned short* es = sbin + (size_t)bb * BCAP;
        for (int i = threadIdx.x; i < nE; i += 256)
            atomicAdd(&scnt[es[i] & (SBW - 1)], 1);
        __syncthreads();
        int n0 = bb * SBW;
        for (int i = threadIdx.x; i < SBW; i += 256)
            if (n0 + i < N_NODES) odeg[n0 + i] = scnt[i];
    }
}

// ---------------- h -> bf16 rows pre-scaled by s_out (computed in-kernel from odeg) ----------------

__global__ __launch_bounds__(256) void hconv(const float4* __restrict__ h,
                                             const int* __restrict__ odeg,
                                             float* __restrict__ s_out,
                                             uint2* __restrict__ hbA,
                                             uint2* __restrict__ hbB) {
    int gid = blockIdx.x * 256 + threadIdx.x;   // one float4 (4 channels) per thread
    const int total = N_NODES * 32;
    if (gid < total) {
        int node = gid >> 5;
        float so = rsqrtf(fmaxf((float)odeg[node], 1.0f));
        if ((gid & 31) == 0) s_out[node] = so;   // persist for fused_layer epilogue
        float4 v = h[gid];
        hbA[gid] = make_uint2(pack_bf2(so * v.x, so * v.y), pack_bf2(so * v.z, so * v.w));
    } else if (gid < total + 32) {
        hbA[total + (gid - total)] = make_uint2(0u, 0u);        // zero row of actA
    } else if (gid < total + 64) {
        hbB[total + (gid - total - 32)] = make_uint2(0u, 0u);   // zero row of actB
    }
}

// ---------------- fused layer: gather-aggregate -> LDS(split-bf16) -> MFMA GEMM (R7 form) ----------------

__global__ __launch_bounds__(256) void fused_layer(const uint4* __restrict__ x,
                                                   const unsigned short* __restrict__ slots,
                                                   const int* __restrict__ deg,
                                                   const s16x8* __restrict__ wpk,
                                                   const float* __restrict__ bias,
                                                   const float* __restrict__ s_out,
                                                   float* __restrict__ outf,
                                                   unsigned short* __restrict__ outb) {
    __shared__ s16x8 mHI[16 * 17];
    __shared__ s16x8 mLO[16 * 17];
    int tid = threadIdx.x;
    int row0 = blockIdx.x * 16;

    // ---- phase 1: aggregate ----
    {
        int nloc = tid >> 4;          // local node 0..15
        int l    = tid & 15;          // chunk: channels l*8 .. l*8+7
        int node = row0 + nloc;
        int dgraw = deg[node];
        int dg = min(dgraw, CAP);
        int base = node * CAP;
        // prefetch all slot indices; OOB -> zero row
        int idx0 = (l      < dg) ? (int)slots[base + l]      : N_NODES;
        int idx1 = (16 + l < dg) ? (int)slots[base + 16 + l] : N_NODES;
        int idx2 = (32 + l < dg) ? (int)slots[base + 32 + l] : N_NODES;

        float a[8];
#pragma unroll
        for (int j = 0; j < 8; j++) a[j] = 0.f;

        int nr = (dg + 7) >> 3;       // rounds of 8 (0..6), no tails
        for (int r = 0; r < nr; r++) {
            int c = r >> 1;
            int v = (c == 0) ? idx0 : ((c == 1) ? idx1 : idx2);
            int k = (r & 1) * 8;
            int s0 = __shfl(v, k + 0, 16), s1 = __shfl(v, k + 1, 16);
            int s2 = __shfl(v, k + 2, 16), s3 = __shfl(v, k + 3, 16);
            int s4 = __shfl(v, k + 4, 16), s5 = __shfl(v, k + 5, 16);
            int s6 = __shfl(v, k + 6, 16), s7 = __shfl(v, k + 7, 16);
            uint4 g0 = x[s0 * 16 + l];
            uint4 g1 = x[s1 * 16 + l];
            uint4 g2 = x[s2 * 16 + l];
            uint4 g3 = x[s3 * 16 + l];
            uint4 g4 = x[s4 * 16 + l];
            uint4 g5 = x[s5 * 16 + l];
            uint4 g6 = x[s6 * 16 + l];
            uint4 g7 = x[s7 * 16 + l];
            acc_uint4(g0, a); acc_uint4(g1, a); acc_uint4(g2, a); acc_uint4(g3, a);
            acc_uint4(g4, a); acc_uint4(g5, a); acc_uint4(g6, a); acc_uint4(g7, a);
        }
        float si = rsqrtf(fmaxf((float)dgraw, 1.0f));
        s16x8 ahi, alo;
#pragma unroll
        for (int j = 0; j < 8; j++) {
            float av = a[j] * si;
            unsigned short hh = f32_to_bf16_rtne(av);
            ahi[j] = (short)hh;
            alo[j] = (short)f32_to_bf16_rtne(av - bf16_to_f32(hh));
        }
        mHI[nloc * 17 + l] = ahi;
        mLO[nloc * 17 + l] = alo;
    }
    __syncthreads();

    // ---- phase 2: GEMM ----
    int wv = tid >> 6;                 // wave 0..3 -> col-tiles {2wv, 2wv+1}
    int lane = tid & 63;
    int arow = lane & 15, aq = lane >> 4;
    int ct0 = wv * 2, ct1 = ct0 + 1;
    f32x4 acc0 = (f32x4)0.f, acc1 = (f32x4)0.f;

#pragma unroll
    for (int ks = 0; ks < 4; ks++) {
        s16x8 ahi = mHI[arow * 17 + ks * 4 + aq];
        s16x8 alo = mLO[arow * 17 + ks * 4 + aq];
        int idx0 = (ct0 * 4 + ks) * 64 + lane;
        int idx1 = (ct1 * 4 + ks) * 64 + lane;
        s16x8 b0h = wpk[idx0], b0l = wpk[idx0 + 2048];
        s16x8 b1h = wpk[idx1], b1l = wpk[idx1 + 2048];
        acc0 = __builtin_amdgcn_mfma_f32_16x16x32_bf16(ahi, b0h, acc0, 0, 0, 0);
        acc0 = __builtin_amdgcn_mfma_f32_16x16x32_bf16(alo, b0h, acc0, 0, 0, 0);
        acc0 = __builtin_amdgcn_mfma_f32_16x16x32_bf16(ahi, b0l, acc0, 0, 0, 0);
        acc1 = __builtin_amdgcn_mfma_f32_16x16x32_bf16(ahi, b1h, acc1, 0, 0, 0);
        acc1 = __builtin_amdgcn_mfma_f32_16x16x32_bf16(alo, b1h, acc1, 0, 0, 0);
        acc1 = __builtin_amdgcn_mfma_f32_16x16x32_bf16(ahi, b1l, acc1, 0, 0, 0);
    }

    // C/D: col = lane&15, row = (lane>>4)*4 + reg
    int crow0 = aq * 4;
    float so4[4];
    if (outb) {
#pragma unroll
        for (int r = 0; r < 4; r++) so4[r] = s_out[row0 + crow0 + r];
    }
    int colA = ct0 * 16 + arow, colB = ct1 * 16 + arow;
    float bA = bias[colA], bB = bias[colB];
#pragma unroll
    for (int r = 0; r < 4; r++) {
        size_t rowoff = (size_t)(row0 + crow0 + r) * D;
        float vA = fmaxf(acc0[r] + bA, 0.f);
        float vB = fmaxf(acc1[r] + bB, 0.f);
        if (outf) { outf[rowoff + colA] = vA; outf[rowoff + colB] = vB; }
        if (outb) {
            outb[rowoff + colA] = f32_to_bf16_rtne(so4[r] * vA);
            outb[rowoff + colB] = f32_to_bf16_rtne(so4[r] * vB);
        }
    }
}

// ---------------- launch ----------------

extern "C" void kernel_launch(void* const* d_in, const int* in_sizes, int n_in,
                              void* d_out, int out_size, void* d_ws, size_t ws_size,
                              hipStream_t stream) {
    const float* h  = (const float*)d_in[0];
    const int*  src = (const int*)d_in[1];
    const int*  dst = (const int*)d_in[2];
    const float* W0 = (const float*)d_in[3];
    const float* b0 = (const float*)d_in[4];
    const float* W1 = (const float*)d_in[5];
    const float* b1 = (const float*)d_in[6];
    const float* W2 = (const float*)d_in[7];
    const float* b2 = (const float*)d_in[8];
    float* out = (float*)d_out;

    char* w = (char*)d_ws;
    auto carve = [&](size_t bytes) -> void* {
        void* p = (void*)w;
        w += (bytes + 255) & ~(size_t)255;
        return p;
    };
    int*      gcurD   = (int*)carve((DNB + 128) * sizeof(int));    // gcurD + gcurS (one memset)
    int*      gcurS   = gcurD + DNB;
    int*      cursor  = (int*)carve(NPADN * sizeof(int));          // in-degree (padded)
    int*      odeg    = (int*)carve(N_NODES * sizeof(int));
    float*    s_out   = (float*)carve(N_NODES * sizeof(float));
    unsigned long long* dbin = (unsigned long long*)carve((size_t)DNB * DCAP * 8);   // 9.6 MB
    unsigned short* slots = (unsigned short*)carve((size_t)NPADN * CAP * sizeof(unsigned short)); // 4.8 MB
    unsigned short* sbin  = (unsigned short*)carve((size_t)SNB * BCAP * sizeof(unsigned short));  // 2.0 MB
    unsigned short* actA  = (unsigned short*)carve((size_t)(N_NODES + 1) * D * 2);  // 12.8 MB (+zero row)
    unsigned short* actB  = (unsigned short*)carve((size_t)(N_NODES + 1) * D * 2);  // 12.8 MB
    s16x8*    wpk     = (s16x8*)carve(3 * 4096 * sizeof(s16x8));                    // 192 KB

    hipMemsetAsync(gcurD, 0, (DNB + 128) * sizeof(int), stream);
    build_bin<<<ABLK + PACKB, 256, 0, stream>>>(src, dst, gcurD, gcurS, dbin, sbin,
                                                W0, W1, W2, wpk);
    fill_sort<<<FNB + SNB, 256, 0, stream>>>(dbin, gcurD, slots, cursor,
                                             sbin, gcurS, odeg);
    hconv<<<(N_NODES * 32 + 64 + 255) / 256, 256, 0, stream>>>((const float4*)h, odeg, s_out,
                                                               (uint2*)actA, (uint2*)actB);

    const int GRID = N_NODES / 16;   // 3125 exact

    // layer 1: actA(bf16, s_out-scaled h) -> actB
    fused_layer<<<GRID, 256, 0, stream>>>((const uint4*)actA, slots, cursor,
                                          wpk, b0, s_out, nullptr, actB);
    // layer 2: actB -> actA
    fused_layer<<<GRID, 256, 0, stream>>>((const uint4*)actB, slots, cursor,
                                          wpk + 4096, b1, s_out, nullptr, actA);
    // layer 3: actA -> d_out (fp32)
    fused_layer<<<GRID, 256, 0, stream>>>((const uint4*)actA, slots, cursor,
                                          wpk + 8192, b2, s_out, out, nullptr);
}